// Round 1
// baseline (640.532 us; speedup 1.0000x reference)
//
#include <hip/hip_runtime.h>

// Problem constants (from reference):
//   aer_feat: (B=4, C=64, HA=512, WA=512) f32
//   pose_uvr: (B=4, N=256, 3) f32
//   out:      (B, N, C, HB=32, WB=32) f32
constexpr int HB_ = 32, WB_ = 32;
constexpr int HA_ = 512, WA_ = 512;
constexpr int C_  = 64,  N_  = 256;

// One block per (b,n) patch. 256 threads; each thread owns 4 consecutive wb
// positions in one patch row -> float4-coalesced output stores.
// Tap indices/weights computed ONCE per position, reused across all 64 channels.
__global__ __launch_bounds__(256) void aps_kernel(
    const float* __restrict__ aer, const float* __restrict__ pose,
    float* __restrict__ out)
{
    const int bn  = blockIdx.x;        // b*N + n
    const int b   = bn >> 8;           // N = 256
    const int tid = threadIdx.x;

    const float u  = pose[bn * 3 + 0];
    const float v  = pose[bn * 3 + 1];
    const float th = pose[bn * 3 + 2];
    float s_r, c_r;
    sincosf(-th, &s_r, &c_r);          // cos(-theta), sin(-theta)

    const int i  = tid >> 3;           // patch row hb: 0..31
    const int j0 = (tid & 7) * 4;      // first of 4 patch cols wb

    // grid_u0 = HB-1-i (rows flipped), grid_v0 = j - WB/2
    const float gu_i = u + c_r * (float)(HB_ - 1 - i);
    const float gv_i = v + s_r * (float)(HB_ - 1 - i);

    int   idx[4][4];
    float w[4][4];
    #pragma unroll
    for (int k = 0; k < 4; ++k) {
        const float gv0 = (float)(j0 + k - WB_ / 2);
        const float gu  = gu_i - s_r * gv0;
        const float gv  = gv_i + c_r * gv0;
        float gx = (gu + 0.5f) * (2.0f / (float)WA_) - 1.0f;
        float gy = (gv + 0.5f) * (2.0f / (float)HA_) - 1.0f;
        const bool valid = (fabsf(gx) < 1.0f) && (fabsf(gy) < 1.0f);
        if (!valid) { gx = 2.0f; gy = 2.0f; }   // ref: invalid -> fully OOB
        // unnormalize (align_corners=False)
        const float ix = ((gx + 1.0f) * (float)WA_ - 1.0f) * 0.5f;
        const float iy = ((gy + 1.0f) * (float)HA_ - 1.0f) * 0.5f;
        const float x0f = floorf(ix), y0f = floorf(iy);
        const float wx1 = ix - x0f, wx0 = 1.0f - wx1;
        const float wy1 = iy - y0f, wy0 = 1.0f - wy1;
        const int x0 = (int)x0f, y0 = (int)y0f;
        const int x1 = x0 + 1,   y1 = y0 + 1;
        const bool vx0 = (x0 >= 0) & (x0 < WA_);
        const bool vx1 = (x1 >= 0) & (x1 < WA_);
        const bool vy0 = (y0 >= 0) & (y0 < HA_);
        const bool vy1 = (y1 >= 0) & (y1 < HA_);
        const int x0c = min(max(x0, 0), WA_ - 1), x1c = min(max(x1, 0), WA_ - 1);
        const int y0c = min(max(y0, 0), HA_ - 1), y1c = min(max(y1, 0), HA_ - 1);
        idx[k][0] = y0c * WA_ + x0c;  w[k][0] = wx0 * wy0 * ((vx0 && vy0) ? 1.0f : 0.0f);
        idx[k][1] = y0c * WA_ + x1c;  w[k][1] = wx1 * wy0 * ((vx1 && vy0) ? 1.0f : 0.0f);
        idx[k][2] = y1c * WA_ + x0c;  w[k][2] = wx0 * wy1 * ((vx0 && vy1) ? 1.0f : 0.0f);
        idx[k][3] = y1c * WA_ + x1c;  w[k][3] = wx1 * wy1 * ((vx1 && vy1) ? 1.0f : 0.0f);
    }

    const float* img = aer + (size_t)b * C_ * (HA_ * WA_);
    float* op = out + (size_t)bn * C_ * (HB_ * WB_) + tid * 4;

    for (int c = 0; c < C_; ++c) {
        const float* im = img + (size_t)c * (HA_ * WA_);
        float rr[4];
        #pragma unroll
        for (int k = 0; k < 4; ++k) {
            rr[k] = w[k][0] * im[idx[k][0]] + w[k][1] * im[idx[k][1]]
                  + w[k][2] * im[idx[k][2]] + w[k][3] * im[idx[k][3]];
        }
        float4 r; r.x = rr[0]; r.y = rr[1]; r.z = rr[2]; r.w = rr[3];
        *(float4*)op = r;
        op += HB_ * WB_;
    }
}

extern "C" void kernel_launch(void* const* d_in, const int* in_sizes, int n_in,
                              void* d_out, int out_size, void* d_ws, size_t ws_size,
                              hipStream_t stream) {
    const float* aer  = (const float*)d_in[0];   // (4,64,512,512) f32
    const float* pose = (const float*)d_in[1];   // (4,256,3) f32
    float* out = (float*)d_out;                  // (4,256,64,32,32) f32
    const int B = 4;
    aps_kernel<<<dim3(B * N_), dim3(256), 0, stream>>>(aer, pose, out);
}

// Round 2
// 486.164 us; speedup vs baseline: 1.3175x; 1.3175x over previous
//
#include <hip/hip_runtime.h>

// aer_feat: (B=4, C=64, HA=512, WA=512) f32
// pose_uvr: (B=4, N=256, 3) f32
// out:      (B, N, C, HB=32, WB=32) f32
constexpr int HB_ = 32, WB_ = 32;
constexpr int HA_ = 512, WA_ = 512;
constexpr int C_  = 64,  N_  = 256;

// Staged bounding box: rotated 32x32 patch spans <= 31*sqrt(2) ~= 43.85 px,
// + bilinear +1 + rounding guard (x_lo -= 1) -> 48x48 covers all taps.
constexpr int SH = 48;            // staged rows
constexpr int SCOLS = 48;         // staged cols (real)
constexpr int SW = 49;            // padded row stride (bank-conflict break)
constexpr int PLANE = SH * SW;    // 2352 elems per channel plane
constexpr int CPR = 4;            // channels per barrier round
constexpr int KST = (SH * SCOLS) / 256;  // 9 staging elems per thread

__global__ __launch_bounds__(256, 4) void aps_kernel(
    const float* __restrict__ aer, const float* __restrict__ pose,
    float* __restrict__ out)
{
    __shared__ float lds[CPR * PLANE];   // 37,632 B

    const int bn  = blockIdx.x;          // b*N + n
    const int b   = bn >> 8;             // N = 256
    const int tid = threadIdx.x;

    const float u  = pose[bn * 3 + 0];
    const float v  = pose[bn * 3 + 1];
    const float th = pose[bn * 3 + 2];
    float s_r, c_r;
    sincosf(-th, &s_r, &c_r);            // sin(-theta), cos(-theta)

    // ---- bounding box of the rotated patch (wave-uniform) ----
    // gu = u + c*gu0 - s*gv0, gu0 in [0,31], gv0 in [-16,15]; x == gu, y == gv
    const float a00 = -s_r * -16.0f,              a01 = -s_r * 15.0f;
    const float a10 = c_r * 31.0f - s_r * -16.0f, a11 = c_r * 31.0f - s_r * 15.0f;
    const float gumin = u + fminf(fminf(a00, a01), fminf(a10, a11));
    const float b00 = c_r * -16.0f,               b01 = c_r * 15.0f;
    const float b10 = s_r * 31.0f + c_r * -16.0f, b11 = s_r * 31.0f + c_r * 15.0f;
    const float gvmin = v + fminf(fminf(b00, b01), fminf(b10, b11));
    const int x_lo = (int)floorf(gumin) - 1;   // -1: rounding guard vs ref chain
    const int y_lo = (int)floorf(gvmin) - 1;

    // ---- per-thread staging offsets (reused for every channel) ----
    int   soff[KST]; int goff[KST]; float gmsk[KST];
    #pragma unroll
    for (int k = 0; k < KST; ++k) {
        const int e  = tid + 256 * k;
        const int r  = e / SCOLS;
        const int cl = e - r * SCOLS;
        const int y  = y_lo + r;
        const int x  = x_lo + cl;
        const bool ok = ((unsigned)y < (unsigned)HA_) && ((unsigned)x < (unsigned)WA_);
        soff[k] = r * SW + cl;
        goff[k] = ok ? (y * WA_ + x) : 0;
        gmsk[k] = ok ? 1.0f : 0.0f;
    }

    // ---- per-position taps (LDS-relative), exact ref arithmetic ----
    const int i  = tid >> 3;             // patch row hb
    const int j0 = (tid & 7) * 4;        // first of 4 patch cols
    const float gu_i = u + c_r * (float)(HB_ - 1 - i);
    const float gv_i = v + s_r * (float)(HB_ - 1 - i);

    int   lbase[4];
    float w[4][4];
    #pragma unroll
    for (int k = 0; k < 4; ++k) {
        const float gv0 = (float)(j0 + k - WB_ / 2);
        const float gu  = gu_i - s_r * gv0;
        const float gv  = gv_i + c_r * gv0;
        float gx = (gu + 0.5f) * (2.0f / (float)WA_) - 1.0f;
        float gy = (gv + 0.5f) * (2.0f / (float)HA_) - 1.0f;
        const bool valid = (fabsf(gx) < 1.0f) && (fabsf(gy) < 1.0f);
        if (!valid) { gx = 2.0f; gy = 2.0f; }
        const float ix = ((gx + 1.0f) * (float)WA_ - 1.0f) * 0.5f;
        const float iy = ((gy + 1.0f) * (float)HA_ - 1.0f) * 0.5f;
        const float x0f = floorf(ix), y0f = floorf(iy);
        const float wx1 = ix - x0f, wx0 = 1.0f - wx1;
        const float wy1 = iy - y0f, wy0 = 1.0f - wy1;
        const int x0 = (int)x0f, y0 = (int)y0f;
        const int x1 = x0 + 1,   y1 = y0 + 1;
        const bool vx0 = (x0 >= 0) & (x0 < WA_);
        const bool vx1 = (x1 >= 0) & (x1 < WA_);
        const bool vy0 = (y0 >= 0) & (y0 < HA_);
        const bool vy1 = (y1 >= 0) & (y1 < HA_);
        w[k][0] = wx0 * wy0 * ((vx0 && vy0) ? 1.0f : 0.0f);
        w[k][1] = wx1 * wy0 * ((vx1 && vy0) ? 1.0f : 0.0f);
        w[k][2] = wx0 * wy1 * ((vx0 && vy1) ? 1.0f : 0.0f);
        w[k][3] = wx1 * wy1 * ((vx1 && vy1) ? 1.0f : 0.0f);
        // LDS-relative tap origin; clamp so +1/+SW/+SW+1 stay in staged area
        // (only zero-weight taps ever clamp)
        const int lx = min(max(x0 - x_lo, 0), SCOLS - 2);
        const int ly = min(max(y0 - y_lo, 0), SH - 2);
        lbase[k] = ly * SW + lx;
    }

    const float* img = aer + (size_t)b * C_ * (HA_ * WA_);
    float* op = out + (size_t)bn * C_ * (HB_ * WB_) + tid * 4;

    for (int c0 = 0; c0 < C_; c0 += CPR) {
        __syncthreads();   // previous round's reads done before overwrite
        #pragma unroll
        for (int cc = 0; cc < CPR; ++cc) {
            const float* im = img + (size_t)(c0 + cc) * (HA_ * WA_);
            float* pl = &lds[cc * PLANE];
            #pragma unroll
            for (int k = 0; k < KST; ++k)
                pl[soff[k]] = im[goff[k]] * gmsk[k];
        }
        __syncthreads();
        #pragma unroll
        for (int cc = 0; cc < CPR; ++cc) {
            const float* p = &lds[cc * PLANE];
            float rr[4];
            #pragma unroll
            for (int k = 0; k < 4; ++k) {
                const int lb = lbase[k];
                rr[k] = w[k][0] * p[lb]      + w[k][1] * p[lb + 1]
                      + w[k][2] * p[lb + SW] + w[k][3] * p[lb + SW + 1];
            }
            float4 r4; r4.x = rr[0]; r4.y = rr[1]; r4.z = rr[2]; r4.w = rr[3];
            *(float4*)(op + (size_t)(c0 + cc) * (HB_ * WB_)) = r4;
        }
    }
}

extern "C" void kernel_launch(void* const* d_in, const int* in_sizes, int n_in,
                              void* d_out, int out_size, void* d_ws, size_t ws_size,
                              hipStream_t stream) {
    const float* aer  = (const float*)d_in[0];   // (4,64,512,512) f32
    const float* pose = (const float*)d_in[1];   // (4,256,3) f32
    float* out = (float*)d_out;                  // (4,256,64,32,32) f32
    const int B = 4;
    aps_kernel<<<dim3(B * N_), dim3(256), 0, stream>>>(aer, pose, out);
}